// Round 5
// baseline (1148.713 us; speedup 1.0000x reference)
//
#include <hip/hip_runtime.h>

typedef __bf16 bf16_t;
typedef __attribute__((ext_vector_type(8))) __bf16 bf16x8;
typedef __attribute__((ext_vector_type(4))) float f32x4;
typedef unsigned short u16;
typedef unsigned int u32;
typedef unsigned long long u64;

#define TC 256
#define NCHUNK 4
#define LDA 264   // 256 + 8 bf16 pad
#define LDB 40    // 32 + 8 pad

// Raw barrier: LDS-visibility only (lgkmcnt), leaves global prefetch loads
// (vmcnt) in flight — avoids the compiler's s_waitcnt vmcnt(0) drain that
// __syncthreads emits before s_barrier (the ~900 cyc/step stall in R4).
#define LDS_BARRIER() asm volatile("s_waitcnt lgkmcnt(0)\n\ts_barrier" ::: "memory")

// ws layout (bytes), total ~72.8 MB:
//   xg2  @ 0         : 64*256*2048*2 = 67,108,864  (bf16 xg chunk, scan-tiled)
//   embb @ 67108864  : 10000*256*2   =  5,120,000
//   wkt  @ 72228864  : 512*256*2     =    262,144
//   hst  @ 72491008  : 64*128*4*4    =    131,072  (f32 h carry [g][u][row4])
//   cst  @ 72622080  : 64*128*4*4    =    131,072  (f32 c carry)
//
// xg2 layout (u16 units): off = ((g*256 + t)*2048) + tile*64 + c16*4 + row4
//   g = b>>2 (scan wg, 64 of them), row4 = b&3, t = chunk-local step,
//   tile = col>>4, c16 = col&15. Scan quad-0 lane (w,l16) reads b64 =
//   rows 0..3 of col 16w+l16+128j from tile w+8j. 4 KB per (g,t) block.

static __device__ __forceinline__ u16 bf16bits(float v) {
  return __builtin_bit_cast(u16, (bf16_t)v);
}
static __device__ __forceinline__ float bf16f(u16 v) {
  return __builtin_bit_cast(float, (u32)v << 16);
}

__global__ __launch_bounds__(256) void k_cvt_emb(const float* __restrict__ e,
                                                 u16* __restrict__ o, int n) {
  int i = blockIdx.x * 256 + threadIdx.x;
  if (i < n) o[i] = bf16bits(e[i]);
}

// WkT[n][k] = Wk[k][n]  (Wk is [256][512] row-major)
__global__ __launch_bounds__(256) void k_wkt(const float* __restrict__ wk,
                                             u16* __restrict__ o) {
  int i = blockIdx.x * 256 + threadIdx.x;  // 131072 total
  int k = i & 255, n = i >> 8;
  o[i] = bf16bits(wk[k * 512 + n]);
}

// xg2[...] = emb[x[...]] @ Wk + bias, bf16, scan-tiled layout.
// wg = (gg, tb): 64 rows = 16 batch rows (b=16gg+row16) x 4 steps (t=tb*4+mt).
__global__ __launch_bounds__(256) void k_xgemm(
    const int* __restrict__ x, const u16* __restrict__ embb,
    const u16* __restrict__ wkt, const float* __restrict__ bias,
    u16* __restrict__ xg, int t0) {
  __shared__ u16 Al[64 * LDA];
  __shared__ u16 Bl[512 * LDB];
  __shared__ float biasl[512];
  const int tid = threadIdx.x;
  const int gg = blockIdx.x >> 6;
  const int tb = blockIdx.x & 63;

  // stage A: 64 gathered rows x 256 bf16
  {
    const int ar = tid >> 5;          // 0..7
    const int c8 = (tid & 31) * 8;    // 0..248
#pragma unroll
    for (int p = 0; p < 8; ++p) {
      int lr = p * 8 + ar;
      int xi = (16 * gg + (lr & 15)) * 1024 + t0 + tb * 4 + (lr >> 4);
      int idx = x[xi];
      *(uint4*)&Al[lr * LDA + c8] = *(const uint4*)&embb[idx * 256 + c8];
    }
    biasl[tid] = bias[tid];
    biasl[tid + 256] = bias[tid + 256];
  }

  const int wv = tid >> 6, lane = tid & 63;
  const int l16 = lane & 15, quad = lane >> 4;
  f32x4 zero = {0.f, 0.f, 0.f, 0.f};
  f32x4 acc[4][8];
#pragma unroll
  for (int mt = 0; mt < 4; ++mt)
#pragma unroll
    for (int nt = 0; nt < 8; ++nt) acc[mt][nt] = zero;

  for (int kt = 0; kt < 8; ++kt) {
    __syncthreads();
#pragma unroll
    for (int q8 = 0; q8 < 8; ++q8) {
      int c = q8 * 256 + tid;
      int rn = c >> 2, q = c & 3;
      *(uint4*)&Bl[rn * LDB + q * 8] = *(const uint4*)&wkt[rn * 256 + kt * 32 + q * 8];
    }
    __syncthreads();
    bf16x8 a[4];
#pragma unroll
    for (int mt = 0; mt < 4; ++mt)
      a[mt] = *(const bf16x8*)&Al[(mt * 16 + l16) * LDA + kt * 32 + quad * 8];
#pragma unroll
    for (int nt = 0; nt < 8; ++nt) {
      bf16x8 bfr = *(const bf16x8*)&Bl[(wv * 128 + nt * 16 + l16) * LDB + quad * 8];
#pragma unroll
      for (int mt = 0; mt < 4; ++mt)
        acc[mt][nt] =
            __builtin_amdgcn_mfma_f32_16x16x32_bf16(a[mt], bfr, acc[mt][nt], 0, 0, 0);
    }
  }

  // epilogue: + bias, pack rows r=0..3 of scan-group g'=4gg+quad into one b64
  const size_t gtbase = ((size_t)(4 * gg + quad) * 256 + tb * 4) * 2048;
#pragma unroll
  for (int nt = 0; nt < 8; ++nt) {
    int col = wv * 128 + nt * 16 + l16;
    float bv = biasl[col];
    int tile = wv * 8 + nt;
#pragma unroll
    for (int mt = 0; mt < 4; ++mt) {
      u64 pk = 0;
#pragma unroll
      for (int r = 0; r < 4; ++r)
        pk |= (u64)bf16bits(acc[mt][nt][r] + bv) << (16 * r);
      size_t off = gtbase + (size_t)mt * 2048 + tile * 64 + l16 * 4;
      *(u64*)&xg[off] = pk;
    }
  }
}

// MFMA scan: 64 wgs x 512 threads; wg g owns batch rows [4g,4g+4) in M-slots
// 0..3 (slots 4..15 held at zero). Wave w: gate tiles {w,w+8,w+16,w+24} =
// gates i,f,c,o of unit col u=16w+l16. Quad-0 lanes own the real rows' cell
// state; all lanes feed MFMA. Wr B-frags in VGPRs. 4-step-deep xg prefetch
// kept in flight across the raw LDS_BARRIER (no vmcnt drain per step).
__global__ __launch_bounds__(512) void k_scan(
    const u16* __restrict__ xg, const float* __restrict__ Wr,
    const float* __restrict__ Wd, const float* __restrict__ bd,
    float* __restrict__ hstf, float* __restrict__ cstf,
    float* __restrict__ out, int chunk) {
  const int g = blockIdx.x;
  const int tid = threadIdx.x;
  const int w = tid >> 6, lane = tid & 63;
  const int l16 = lane & 15, quad = lane >> 4;
  const int u = 16 * w + l16;

  __shared__ u16 hbuf[2][16 * 136];

  // preload Wr fragments: wf[j][kt][jj] = bf16(Wr[kt*32+quad*8+jj][u+128j])
  bf16x8 wf[4][4];
#pragma unroll
  for (int j = 0; j < 4; ++j)
#pragma unroll
    for (int kt = 0; kt < 4; ++kt) {
      const float* p = Wr + (kt * 32 + quad * 8) * 512 + u + 128 * j;
#pragma unroll
      for (int jj = 0; jj < 8; ++jj) wf[j][kt][jj] = (bf16_t)p[jj * 512];
    }

  // init h, c: zero both buffers, then carry into rows 0..3 of buf 0.
  for (int i = tid; i < 2 * 16 * 136; i += 512) hbuf[0][i] = 0;
  __syncthreads();
  f32x4 c4 = {0.f, 0.f, 0.f, 0.f};
  if (chunk != 0 && quad == 0) {
    c4 = *(const f32x4*)&cstf[(g * 128 + u) * 4];
    f32x4 h4 = *(const f32x4*)&hstf[(g * 128 + u) * 4];
#pragma unroll
    for (int r = 0; r < 4; ++r)
      hbuf[0][r * 136 + u] = bf16bits(h4[r]);
  }

  const u16* xbase = xg + (size_t)g * TC * 2048;
  const int xoff0 = w * 64 + l16 * 4;  // tile w + col l16, rows 0..3

  // 4-slot rotating prefetch (distance 4 covers ~2400 cyc of HBM latency)
  u64 xq[4][4];
  if (quad == 0) {
#pragma unroll
    for (int s = 0; s < 4; ++s)
#pragma unroll
      for (int j = 0; j < 4; ++j)
        xq[s][j] = *(const u64*)&xbase[(size_t)s * 2048 + 8 * j * 64 + xoff0];
  }

  __syncthreads();

  f32x4 hl = {0.f, 0.f, 0.f, 0.f};

  auto step = [&](int t) {
    const u16* hb = &hbuf[t & 1][0];
    u16* hn = &hbuf[(t & 1) ^ 1][0];
    bf16x8 a[4];
#pragma unroll
    for (int kt = 0; kt < 4; ++kt)
      a[kt] = *(const bf16x8*)&hb[l16 * 136 + kt * 32 + quad * 8];
    // unpack this step's xg (independent of MFMA, hide behind it) + re-prefetch
    float xf[4][4];
    if (quad == 0) {
      u64* xgv = xq[t & 3];
#pragma unroll
      for (int j = 0; j < 4; ++j)
#pragma unroll
        for (int r = 0; r < 4; ++r)
          xf[j][r] = bf16f((u16)(xgv[j] >> (16 * r)));
      int pft = t + 4 < TC ? t + 4 : TC - 1;
#pragma unroll
      for (int j = 0; j < 4; ++j)
        xgv[j] = *(const u64*)&xbase[(size_t)pft * 2048 + 8 * j * 64 + xoff0];
    }
    f32x4 acc[4];
#pragma unroll
    for (int j = 0; j < 4; ++j) acc[j] = f32x4{0.f, 0.f, 0.f, 0.f};
#pragma unroll
    for (int j = 0; j < 4; ++j)
#pragma unroll
      for (int kt = 0; kt < 4; ++kt)
        acc[j] = __builtin_amdgcn_mfma_f32_16x16x32_bf16(a[kt], wf[j][kt], acc[j], 0, 0, 0);
    if (quad == 0) {
      // acc[0..3][r] = zi,zf,zc,zo for batch-row r, unit col u
#pragma unroll
      for (int r = 0; r < 4; ++r) {
        float zi = acc[0][r] + xf[0][r];
        float zf = acc[1][r] + xf[1][r];
        float zc = acc[2][r] + xf[2][r];
        float zo = acc[3][r] + xf[3][r];
        float ig = __builtin_amdgcn_rcpf(1.f + __expf(-zi));
        float fg = __builtin_amdgcn_rcpf(1.f + __expf(-zf));
        float og = __builtin_amdgcn_rcpf(1.f + __expf(-zo));
        float gg = fmaxf(zc, 0.f);
        c4[r] = fg * c4[r] + ig * gg;
        float hr = og * fmaxf(c4[r], 0.f);
        hl[r] = hr;
        hn[r * 136 + u] = bf16bits(hr);
      }
    }
    LDS_BARRIER();
  };

#pragma unroll 4
  for (int t = 0; t < TC; ++t) step(t);

  if (chunk != NCHUNK - 1) {
    if (quad == 0) {
      *(f32x4*)&cstf[(g * 128 + u) * 4] = c4;
      *(f32x4*)&hstf[(g * 128 + u) * 4] = hl;
    }
  } else if (tid < 8) {
    // final h is in hbuf[0] rows 0..3 (t=255 wrote buf 0; barrier passed)
    int row = tid >> 1, jo = tid & 1;
    float o = bd[jo];
    for (int k = 0; k < 128; ++k)
      o += bf16f(hbuf[0][row * 136 + k]) * Wd[k * 2 + jo];
    out[(g * 4 + row) * 2 + jo] = o;
  }
}

extern "C" void kernel_launch(void* const* d_in, const int* in_sizes, int n_in,
                              void* d_out, int out_size, void* d_ws, size_t ws_size,
                              hipStream_t stream) {
  const int* x = (const int*)d_in[0];
  const float* emb = (const float*)d_in[1];
  const float* Wk = (const float*)d_in[2];
  const float* Wr = (const float*)d_in[3];
  const float* bias = (const float*)d_in[4];
  const float* Wd = (const float*)d_in[5];
  const float* bd = (const float*)d_in[6];
  float* out = (float*)d_out;
  char* ws = (char*)d_ws;
  u16* xg = (u16*)(ws);
  u16* embb = (u16*)(ws + 67108864);
  u16* wkt = (u16*)(ws + 72228864);
  float* hst = (float*)(ws + 72491008);
  float* cst = (float*)(ws + 72622080);

  k_cvt_emb<<<10000, 256, 0, stream>>>(emb, embb, 2560000);
  k_wkt<<<512, 256, 0, stream>>>(Wk, wkt);
  for (int chunk = 0; chunk < NCHUNK; ++chunk) {
    k_xgemm<<<1024, 256, 0, stream>>>(x, embb, wkt, bias, xg, chunk * TC);
    k_scan<<<64, 512, 0, stream>>>(xg, Wr, Wd, bd, hst, cst, out, chunk);
  }
}

// Round 6
// 793.466 us; speedup vs baseline: 1.4477x; 1.4477x over previous
//
#include <hip/hip_runtime.h>

typedef __bf16 bf16_t;
typedef __attribute__((ext_vector_type(8))) __bf16 bf16x8;
typedef __attribute__((ext_vector_type(4))) float f32x4;
typedef unsigned short u16;
typedef unsigned int u32;
typedef unsigned long long u64;

#define TC 256
#define NCHUNK 4
#define LDA 264   // 256 + 8 bf16 pad
#define LDB 40    // 32 + 8 pad

// LDS-visibility-only barrier: leaves global prefetch loads (vmcnt) in flight.
#define LDS_BARRIER() asm volatile("s_waitcnt lgkmcnt(0)\n\ts_barrier" ::: "memory")

// ws layout (bytes), total ~72.8 MB:
//   xg2  @ 0         : 64*256*2048*2 = 67,108,864  (bf16 xg chunk, scan-tiled)
//   embb @ 67108864  : 10000*256*2   =  5,120,000
//   wkt  @ 72228864  : 512*256*2     =    262,144
//   hst  @ 72491008  : 64*4*128*4    =    131,072  (f32 h carry [g][p][u])
//   cst  @ 72622080  : 64*4*128*4    =    131,072  (f32 c carry)
//
// xg2 layout (u16): off = ((g*256 + t)*2048) + tile*64 + c16*4 + row4
//   g = b>>2, row4 = b&3 (= p), tile = col>>4, c16 = col&15.
//   Scan lane (w,quad,l16) gate j reads u16 at (w+8j)*64 + l16*4 + quad
//   (one dense 128-B block per wave per j -> fully coalesced).

static __device__ __forceinline__ u16 bf16bits(float v) {
  return __builtin_bit_cast(u16, (bf16_t)v);
}
static __device__ __forceinline__ float bf16f(u16 v) {
  return __builtin_bit_cast(float, (u32)v << 16);
}

__global__ __launch_bounds__(256) void k_cvt_emb(const float* __restrict__ e,
                                                 u16* __restrict__ o, int n) {
  int i = blockIdx.x * 256 + threadIdx.x;
  if (i < n) o[i] = bf16bits(e[i]);
}

// WkT[n][k] = Wk[k][n]  (Wk is [256][512] row-major)
__global__ __launch_bounds__(256) void k_wkt(const float* __restrict__ wk,
                                             u16* __restrict__ o) {
  int i = blockIdx.x * 256 + threadIdx.x;  // 131072 total
  int k = i & 255, n = i >> 8;
  o[i] = bf16bits(wk[k * 512 + n]);
}

// xg2[...] = emb[x[...]] @ Wk + bias, bf16, scan-tiled layout. (unchanged)
__global__ __launch_bounds__(256) void k_xgemm(
    const int* __restrict__ x, const u16* __restrict__ embb,
    const u16* __restrict__ wkt, const float* __restrict__ bias,
    u16* __restrict__ xg, int t0) {
  __shared__ u16 Al[64 * LDA];
  __shared__ u16 Bl[512 * LDB];
  __shared__ float biasl[512];
  const int tid = threadIdx.x;
  const int gg = blockIdx.x >> 6;
  const int tb = blockIdx.x & 63;

  {
    const int ar = tid >> 5;          // 0..7
    const int c8 = (tid & 31) * 8;    // 0..248
#pragma unroll
    for (int p = 0; p < 8; ++p) {
      int lr = p * 8 + ar;
      int xi = (16 * gg + (lr & 15)) * 1024 + t0 + tb * 4 + (lr >> 4);
      int idx = x[xi];
      *(uint4*)&Al[lr * LDA + c8] = *(const uint4*)&embb[idx * 256 + c8];
    }
    biasl[tid] = bias[tid];
    biasl[tid + 256] = bias[tid + 256];
  }

  const int wv = tid >> 6, lane = tid & 63;
  const int l16 = lane & 15, quad = lane >> 4;
  f32x4 zero = {0.f, 0.f, 0.f, 0.f};
  f32x4 acc[4][8];
#pragma unroll
  for (int mt = 0; mt < 4; ++mt)
#pragma unroll
    for (int nt = 0; nt < 8; ++nt) acc[mt][nt] = zero;

  for (int kt = 0; kt < 8; ++kt) {
    __syncthreads();
#pragma unroll
    for (int q8 = 0; q8 < 8; ++q8) {
      int c = q8 * 256 + tid;
      int rn = c >> 2, q = c & 3;
      *(uint4*)&Bl[rn * LDB + q * 8] = *(const uint4*)&wkt[rn * 256 + kt * 32 + q * 8];
    }
    __syncthreads();
    bf16x8 a[4];
#pragma unroll
    for (int mt = 0; mt < 4; ++mt)
      a[mt] = *(const bf16x8*)&Al[(mt * 16 + l16) * LDA + kt * 32 + quad * 8];
#pragma unroll
    for (int nt = 0; nt < 8; ++nt) {
      bf16x8 bfr = *(const bf16x8*)&Bl[(wv * 128 + nt * 16 + l16) * LDB + quad * 8];
#pragma unroll
      for (int mt = 0; mt < 4; ++mt)
        acc[mt][nt] =
            __builtin_amdgcn_mfma_f32_16x16x32_bf16(a[mt], bfr, acc[mt][nt], 0, 0, 0);
    }
  }

  // epilogue: + bias, pack rows r=0..3 of scan-group g'=4gg+quad into one b64
  const size_t gtbase = ((size_t)(4 * gg + quad) * 256 + tb * 4) * 2048;
#pragma unroll
  for (int nt = 0; nt < 8; ++nt) {
    int col = wv * 128 + nt * 16 + l16;
    float bv = biasl[col];
    int tile = wv * 8 + nt;
#pragma unroll
    for (int mt = 0; mt < 4; ++mt) {
      u64 pk = 0;
#pragma unroll
      for (int r = 0; r < 4; ++r)
        pk |= (u64)bf16bits(acc[mt][nt][r] + bv) << (16 * r);
      size_t off = gtbase + (size_t)mt * 2048 + tile * 64 + l16 * 4;
      *(u64*)&xg[off] = pk;
    }
  }
}

// MFMA scan, full-lane gates: 64 wgs x 512 thr; wg g owns batch rows 4g..4g+3
// mapped to M-slots {0,4,8,12}. C/D row quad*4+r is real iff r==0 -> EVERY
// lane (quad,l16) owns one unit: batch row p=quad, col u=16w+l16, gates
// acc[0..3][0]. h kept in 4 compact LDS rows (stride 144 u16); zero M-slots
// synthesized from constant-zero A registers (no LDS read/instr for them).
__global__ __launch_bounds__(512) void k_scan(
    const u16* __restrict__ xg, const float* __restrict__ Wr,
    const float* __restrict__ Wd, const float* __restrict__ bd,
    float* __restrict__ hstf, float* __restrict__ cstf,
    float* __restrict__ out, int chunk) {
  const int g = blockIdx.x;
  const int tid = threadIdx.x;
  const int w = tid >> 6, lane = tid & 63;
  const int l16 = lane & 15, quad = lane >> 4;
  const int u = 16 * w + l16;

  __shared__ u16 hbuf[2][4 * 144];

  // preload Wr fragments: wf[j][kt][jj] = bf16(Wr[kt*32+quad*8+jj][u+128j])
  bf16x8 wf[4][4];
#pragma unroll
  for (int j = 0; j < 4; ++j)
#pragma unroll
    for (int kt = 0; kt < 4; ++kt) {
      const float* p = Wr + (kt * 32 + quad * 8) * 512 + u + 128 * j;
#pragma unroll
      for (int jj = 0; jj < 8; ++jj) wf[j][kt][jj] = (bf16_t)p[jj * 512];
    }

  // init carry (each lane: batch row quad, col u)
  float c1 = 0.f, h1 = 0.f;
  if (chunk != 0) {
    c1 = cstf[(g * 4 + quad) * 128 + u];
    h1 = hstf[(g * 4 + quad) * 128 + u];
  }
  hbuf[0][quad * 144 + u] = bf16bits(h1);

  // xg lane pointer (old layout): gate j at xlane[t*2048 + j*512]
  const u16* xlane = xg + (size_t)g * TC * 2048 + w * 64 + l16 * 4 + quad;
  u16 xq[2][4];
#pragma unroll
  for (int s = 0; s < 2; ++s)
#pragma unroll
    for (int j = 0; j < 4; ++j) xq[s][j] = xlane[s * 2048 + j * 512];

  __syncthreads();

  const bool ald = (l16 & 3) == 0;   // A-fragment loader lanes (slots 0,4,8,12)
  const int pbase = (l16 >> 2) * 144;
  bf16x8 bzero;
#pragma unroll
  for (int z = 0; z < 8; ++z) bzero[z] = (bf16_t)0.0f;

  auto step = [&](int t) {
    const u16* hb = &hbuf[t & 1][0];
    u16* hn = &hbuf[(t & 1) ^ 1][0];
    bf16x8 a[4];
#pragma unroll
    for (int kt = 0; kt < 4; ++kt) {
      a[kt] = bzero;
      if (ald) a[kt] = *(const bf16x8*)&hb[pbase + kt * 32 + quad * 8];
    }
    // unpack this step's gates, re-prefetch 2 ahead (stays in flight across barrier)
    float xf[4];
#pragma unroll
    for (int j = 0; j < 4; ++j) xf[j] = bf16f(xq[t & 1][j]);
    int pft = t + 2 < TC ? t + 2 : t;
#pragma unroll
    for (int j = 0; j < 4; ++j) xq[t & 1][j] = xlane[(size_t)pft * 2048 + j * 512];

    f32x4 acc[4];
#pragma unroll
    for (int j = 0; j < 4; ++j) acc[j] = f32x4{0.f, 0.f, 0.f, 0.f};
#pragma unroll
    for (int j = 0; j < 4; ++j)
#pragma unroll
      for (int kt = 0; kt < 4; ++kt)
        acc[j] = __builtin_amdgcn_mfma_f32_16x16x32_bf16(a[kt], wf[j][kt], acc[j], 0, 0, 0);

    // every lane: one unit (row quad, col u); acc[j][0] = zi,zf,zc,zo
    float zi = acc[0][0] + xf[0];
    float zf = acc[1][0] + xf[1];
    float zc = acc[2][0] + xf[2];
    float zo = acc[3][0] + xf[3];
    float ig = __builtin_amdgcn_rcpf(1.f + __expf(-zi));
    float fg = __builtin_amdgcn_rcpf(1.f + __expf(-zf));
    float og = __builtin_amdgcn_rcpf(1.f + __expf(-zo));
    float gg = fmaxf(zc, 0.f);
    c1 = fg * c1 + ig * gg;
    h1 = og * fmaxf(c1, 0.f);
    hn[quad * 144 + u] = bf16bits(h1);
    LDS_BARRIER();
  };

#pragma unroll 2
  for (int t = 0; t < TC; ++t) step(t);

  if (chunk != NCHUNK - 1) {
    cstf[(g * 4 + quad) * 128 + u] = c1;
    hstf[(g * 4 + quad) * 128 + u] = h1;
  } else if (tid < 8) {
    // final h is in hbuf[0] (t=255 wrote buf 0; barrier passed)
    int p = tid >> 1, jo = tid & 1;
    float o = bd[jo];
    for (int k = 0; k < 128; ++k)
      o += bf16f(hbuf[0][p * 144 + k]) * Wd[k * 2 + jo];
    out[(g * 4 + p) * 2 + jo] = o;
  }
}

extern "C" void kernel_launch(void* const* d_in, const int* in_sizes, int n_in,
                              void* d_out, int out_size, void* d_ws, size_t ws_size,
                              hipStream_t stream) {
  const int* x = (const int*)d_in[0];
  const float* emb = (const float*)d_in[1];
  const float* Wk = (const float*)d_in[2];
  const float* Wr = (const float*)d_in[3];
  const float* bias = (const float*)d_in[4];
  const float* Wd = (const float*)d_in[5];
  const float* bd = (const float*)d_in[6];
  float* out = (float*)d_out;
  char* ws = (char*)d_ws;
  u16* xg = (u16*)(ws);
  u16* embb = (u16*)(ws + 67108864);
  u16* wkt = (u16*)(ws + 72228864);
  float* hst = (float*)(ws + 72491008);
  float* cst = (float*)(ws + 72622080);

  k_cvt_emb<<<10000, 256, 0, stream>>>(emb, embb, 2560000);
  k_wkt<<<512, 256, 0, stream>>>(Wk, wkt);
  for (int chunk = 0; chunk < NCHUNK; ++chunk) {
    k_xgemm<<<1024, 256, 0, stream>>>(x, embb, wkt, bias, xg, chunk * TC);
    k_scan<<<64, 512, 0, stream>>>(xg, Wr, Wd, bd, hst, cst, out, chunk);
  }
}

// Round 7
// 783.968 us; speedup vs baseline: 1.4653x; 1.0121x over previous
//
#include <hip/hip_runtime.h>

typedef __bf16 bf16_t;
typedef __attribute__((ext_vector_type(8))) __bf16 bf16x8;
typedef __attribute__((ext_vector_type(4))) float f32x4;
typedef unsigned short u16;
typedef unsigned int u32;
typedef unsigned long long u64;

#define TC 256
#define NCHUNK 4
#define LDA 264   // 256 + 8 bf16 pad
#define LDB 40    // 32 + 8 pad
#define LOG2E 1.44269504f

// LDS-visibility-only barrier: leaves global prefetch loads (vmcnt) in flight.
#define LDS_BARRIER() asm volatile("s_waitcnt lgkmcnt(0)\n\ts_barrier" ::: "memory")

#if __has_builtin(__builtin_amdgcn_exp2f)
#define EXP2F __builtin_amdgcn_exp2f
#else
static __device__ __forceinline__ float EXP2F(float x) {
  float r;
  asm volatile("v_exp_f32 %0, %1\n\ts_nop 1" : "=v"(r) : "v"(x));
  return r;
}
#endif

// ws layout (bytes), total ~72.8 MB:
//   xg2  @ 0         : 64*256*2048*2 = 67,108,864  (bf16 xg chunk, scan-tiled,
//                       gates i,f,o pre-scaled by -log2e; gate c unscaled)
//   embb @ 67108864  : 10000*256*2   =  5,120,000
//   wkt  @ 72228864  : 512*256*2     =    262,144
//   hst  @ 72491008  : 64*4*128*4    =    131,072  (f32 h carry [g][p][u])
//   cst  @ 72622080  : 64*4*128*4    =    131,072  (f32 c carry)
//
// xg2 layout (u16): off = ((g*256 + t)*2048) + tile*64 + c16*4 + row4
//   g = b>>2, row4 = b&3 (= p), tile = col>>4, c16 = col&15.
//   Scan lane (w,quad,l16) gate j reads u16 at (w+8j)*64 + l16*4 + quad.

static __device__ __forceinline__ u16 bf16bits(float v) {
  return __builtin_bit_cast(u16, (bf16_t)v);
}
static __device__ __forceinline__ float bf16f(u16 v) {
  return __builtin_bit_cast(float, (u32)v << 16);
}

__global__ __launch_bounds__(256) void k_cvt_emb(const float* __restrict__ e,
                                                 u16* __restrict__ o, int n) {
  int i = blockIdx.x * 256 + threadIdx.x;
  if (i < n) o[i] = bf16bits(e[i]);
}

// WkT[n][k] = Wk[k][n]  (Wk is [256][512] row-major)
__global__ __launch_bounds__(256) void k_wkt(const float* __restrict__ wk,
                                             u16* __restrict__ o) {
  int i = blockIdx.x * 256 + threadIdx.x;  // 131072 total
  int k = i & 255, n = i >> 8;
  o[i] = bf16bits(wk[k * 512 + n]);
}

// xg2[...] = (emb[x[...]] @ Wk + bias) * gate_scale, bf16, scan-tiled layout.
// gate_scale = -log2e for gates i,f,o (wv 0,1,3), +1 for gate c (wv 2) —
// lets the scan compute sigmoid as rcp(1+exp2(z')) with zero extra VALU.
__global__ __launch_bounds__(256) void k_xgemm(
    const int* __restrict__ x, const u16* __restrict__ embb,
    const u16* __restrict__ wkt, const float* __restrict__ bias,
    u16* __restrict__ xg, int t0) {
  __shared__ u16 Al[64 * LDA];
  __shared__ u16 Bl[512 * LDB];
  __shared__ float biasl[512];
  const int tid = threadIdx.x;
  const int gg = blockIdx.x >> 6;
  const int tb = blockIdx.x & 63;

  {
    const int ar = tid >> 5;          // 0..7
    const int c8 = (tid & 31) * 8;    // 0..248
#pragma unroll
    for (int p = 0; p < 8; ++p) {
      int lr = p * 8 + ar;
      int xi = (16 * gg + (lr & 15)) * 1024 + t0 + tb * 4 + (lr >> 4);
      int idx = x[xi];
      *(uint4*)&Al[lr * LDA + c8] = *(const uint4*)&embb[idx * 256 + c8];
    }
    biasl[tid] = bias[tid];
    biasl[tid + 256] = bias[tid + 256];
  }

  const int wv = tid >> 6, lane = tid & 63;
  const int l16 = lane & 15, quad = lane >> 4;
  f32x4 zero = {0.f, 0.f, 0.f, 0.f};
  f32x4 acc[4][8];
#pragma unroll
  for (int mt = 0; mt < 4; ++mt)
#pragma unroll
    for (int nt = 0; nt < 8; ++nt) acc[mt][nt] = zero;

  for (int kt = 0; kt < 8; ++kt) {
    __syncthreads();
#pragma unroll
    for (int q8 = 0; q8 < 8; ++q8) {
      int c = q8 * 256 + tid;
      int rn = c >> 2, q = c & 3;
      *(uint4*)&Bl[rn * LDB + q * 8] = *(const uint4*)&wkt[rn * 256 + kt * 32 + q * 8];
    }
    __syncthreads();
    bf16x8 a[4];
#pragma unroll
    for (int mt = 0; mt < 4; ++mt)
      a[mt] = *(const bf16x8*)&Al[(mt * 16 + l16) * LDA + kt * 32 + quad * 8];
#pragma unroll
    for (int nt = 0; nt < 8; ++nt) {
      bf16x8 bfr = *(const bf16x8*)&Bl[(wv * 128 + nt * 16 + l16) * LDB + quad * 8];
#pragma unroll
      for (int mt = 0; mt < 4; ++mt)
        acc[mt][nt] =
            __builtin_amdgcn_mfma_f32_16x16x32_bf16(a[mt], bfr, acc[mt][nt], 0, 0, 0);
    }
  }

  // epilogue: (acc + bias) * gate_scale, pack rows r=0..3 of g'=4gg+quad
  const float gsc = (wv == 2) ? 1.0f : -LOG2E;
  const size_t gtbase = ((size_t)(4 * gg + quad) * 256 + tb * 4) * 2048;
#pragma unroll
  for (int nt = 0; nt < 8; ++nt) {
    int col = wv * 128 + nt * 16 + l16;
    float bv = biasl[col];
    int tile = wv * 8 + nt;
#pragma unroll
    for (int mt = 0; mt < 4; ++mt) {
      u64 pk = 0;
#pragma unroll
      for (int r = 0; r < 4; ++r)
        pk |= (u64)bf16bits((acc[mt][nt][r] + bv) * gsc) << (16 * r);
      size_t off = gtbase + (size_t)mt * 2048 + tile * 64 + l16 * 4;
      *(u64*)&xg[off] = pk;
    }
  }
}

// MFMA scan, minimal-VALU step: 64 wgs x 512 thr; wg g owns batch rows
// 4g..4g+3 in M-slots {0,4,8,12}; every lane owns unit (row quad, col
// u=16w+l16), gates acc[0..3][0]. All per-step addresses are lane-constant
// (precomputed, buf0/buf1 alternate statically); non-loader lanes read a
// zeroed LDS region (broadcast); xg seeds the MFMA C operand; gate weights
// pre-scaled by -log2e so sigmoid = rcp(1+exp2(z')).
__global__ __launch_bounds__(512) void k_scan(
    const u16* __restrict__ xg, const float* __restrict__ Wr,
    const float* __restrict__ Wd, const float* __restrict__ bd,
    float* __restrict__ hstf, float* __restrict__ cstf,
    float* __restrict__ out, int chunk) {
  const int g = blockIdx.x;
  const int tid = threadIdx.x;
  const int w = tid >> 6, lane = tid & 63;
  const int l16 = lane & 15, quad = lane >> 4;
  const int u = 16 * w + l16;

  __shared__ __align__(16) u16 hbuf[2][4 * 144];
  __shared__ __align__(16) u16 zrow[128];

  // preload Wr fragments, gate-scaled: wf[j][kt][jj] =
  //   bf16(Wr[kt*32+quad*8+jj][u+128j] * (j==2 ? 1 : -log2e))
  bf16x8 wf[4][4];
#pragma unroll
  for (int j = 0; j < 4; ++j) {
    const float sj = (j == 2) ? 1.0f : -LOG2E;
#pragma unroll
    for (int kt = 0; kt < 4; ++kt) {
      const float* p = Wr + (kt * 32 + quad * 8) * 512 + u + 128 * j;
#pragma unroll
      for (int jj = 0; jj < 8; ++jj) wf[j][kt][jj] = (bf16_t)(p[jj * 512] * sj);
    }
  }

  if (tid < 128) zrow[tid] = 0;

  // carry (each lane: batch row quad, col u)
  float c1 = 0.f, h1 = 0.f;
  if (chunk != 0) {
    c1 = cstf[(g * 4 + quad) * 128 + u];
    h1 = hstf[(g * 4 + quad) * 128 + u];
  }
  hbuf[0][quad * 144 + u] = bf16bits(h1);

  // lane-constant LDS addresses (A-read per buf, h-write per buf)
  const bool ald = (l16 & 3) == 0;
  const u16* rd0 = ald ? &hbuf[0][(l16 >> 2) * 144 + quad * 8] : &zrow[quad * 8];
  const u16* rd1 = ald ? &hbuf[1][(l16 >> 2) * 144 + quad * 8] : &zrow[quad * 8];
  u16* wr0 = &hbuf[0][quad * 144 + u];
  u16* wr1 = &hbuf[1][quad * 144 + u];

  // xg pointer: gate j at xp[j*512]; advance 2048 u16 per step (2 ahead)
  const u16* xp = xg + (size_t)g * TC * 2048 + w * 64 + l16 * 4 + quad;
  u16 xq0[4], xq1[4];
#pragma unroll
  for (int j = 0; j < 4; ++j) xq0[j] = xp[j * 512];
#pragma unroll
  for (int j = 0; j < 4; ++j) xq1[j] = xp[2048 + j * 512];
  xp += 2 * 2048;

  __syncthreads();

  auto halfstep = [&](const u16* rd, u16* wr, u16* xv) {
    bf16x8 a[4];
#pragma unroll
    for (int kt = 0; kt < 4; ++kt)
      a[kt] = *(const bf16x8*)(rd + kt * 32);  // imm offsets kt*64 B
    f32x4 acc[4];
#pragma unroll
    for (int j = 0; j < 4; ++j)
      acc[j] = f32x4{bf16f(xv[j]), 0.f, 0.f, 0.f};  // C-seed = xg
#pragma unroll
    for (int j = 0; j < 4; ++j)
#pragma unroll
      for (int kt = 0; kt < 4; ++kt)
        acc[j] = __builtin_amdgcn_mfma_f32_16x16x32_bf16(a[kt], wf[j][kt], acc[j], 0, 0, 0);
    // re-prefetch (2 steps ahead; stays in flight across barrier)
#pragma unroll
    for (int j = 0; j < 4; ++j) xv[j] = xp[j * 512];
    xp += 2048;
    // gates: acc[0,1,3][0] = -log2e * z_{i,f,o}; acc[2][0] = z_c
    float ig = __builtin_amdgcn_rcpf(1.f + EXP2F(acc[0][0]));
    float fg = __builtin_amdgcn_rcpf(1.f + EXP2F(acc[1][0]));
    float og = __builtin_amdgcn_rcpf(1.f + EXP2F(acc[3][0]));
    float gg = fmaxf(acc[2][0], 0.f);
    c1 = fg * c1 + ig * gg;
    h1 = og * fmaxf(c1, 0.f);
    *wr = bf16bits(h1);
    LDS_BARRIER();
  };

  for (int t2 = 0; t2 < TC; t2 += 2) {
    halfstep(rd0, wr1, xq0);  // even t: read buf0, write buf1
    halfstep(rd1, wr0, xq1);  // odd t:  read buf1, write buf0
  }

  if (chunk != NCHUNK - 1) {
    cstf[(g * 4 + quad) * 128 + u] = c1;
    hstf[(g * 4 + quad) * 128 + u] = h1;
  } else if (tid < 8) {
    // final h is in hbuf[0] (t=255 wrote buf 0; barrier passed)
    int p = tid >> 1, jo = tid & 1;
    float o = bd[jo];
    for (int k = 0; k < 128; ++k)
      o += bf16f(hbuf[0][p * 144 + k]) * Wd[k * 2 + jo];
    out[(g * 4 + p) * 2 + jo] = o;
  }
}

extern "C" void kernel_launch(void* const* d_in, const int* in_sizes, int n_in,
                              void* d_out, int out_size, void* d_ws, size_t ws_size,
                              hipStream_t stream) {
  const int* x = (const int*)d_in[0];
  const float* emb = (const float*)d_in[1];
  const float* Wk = (const float*)d_in[2];
  const float* Wr = (const float*)d_in[3];
  const float* bias = (const float*)d_in[4];
  const float* Wd = (const float*)d_in[5];
  const float* bd = (const float*)d_in[6];
  float* out = (float*)d_out;
  char* ws = (char*)d_ws;
  u16* xg = (u16*)(ws);
  u16* embb = (u16*)(ws + 67108864);
  u16* wkt = (u16*)(ws + 72228864);
  float* hst = (float*)(ws + 72491008);
  float* cst = (float*)(ws + 72622080);

  k_cvt_emb<<<10000, 256, 0, stream>>>(emb, embb, 2560000);
  k_wkt<<<512, 256, 0, stream>>>(Wk, wkt);
  for (int chunk = 0; chunk < NCHUNK; ++chunk) {
    k_xgemm<<<1024, 256, 0, stream>>>(x, embb, wkt, bias, xg, chunk * TC);
    k_scan<<<64, 512, 0, stream>>>(xg, Wr, Wd, bd, hst, cst, out, chunk);
  }
}

// Round 8
// 750.794 us; speedup vs baseline: 1.5300x; 1.0442x over previous
//
#include <hip/hip_runtime.h>

typedef __bf16 bf16_t;
typedef __attribute__((ext_vector_type(8))) __bf16 bf16x8;
typedef __attribute__((ext_vector_type(4))) float f32x4;
typedef unsigned short u16;
typedef unsigned int u32;
typedef unsigned long long u64;

#define TC 256
#define NCHUNK 4
#define LDA 264   // 256 + 8 bf16 pad
#define LOG2E 1.44269504f

// LDS-visibility-only barrier: leaves global prefetch loads (vmcnt) in flight.
#define LDS_BARRIER() asm volatile("s_waitcnt lgkmcnt(0)\n\ts_barrier" ::: "memory")

#if __has_builtin(__builtin_amdgcn_exp2f)
#define EXP2F __builtin_amdgcn_exp2f
#else
static __device__ __forceinline__ float EXP2F(float x) {
  float r;
  asm volatile("v_exp_f32 %0, %1\n\ts_nop 1" : "=v"(r) : "v"(x));
  return r;
}
#endif

// ws layout (bytes), total ~72.8 MB:
//   xg2  @ 0         : 64*256*2048*2 = 67,108,864  (bf16 xg chunk, scan-tiled,
//                       gates i,f,o pre-scaled by -log2e; gate c unscaled)
//   embb @ 67108864  : 10000*256*2   =  5,120,000
//   wkt  @ 72228864  : 512*256*2     =    262,144
//   hst  @ 72491008  : 64*4*128*4    =    131,072  (f32 h carry [g][p][u])
//   cst  @ 72622080  : 64*4*128*4    =    131,072  (f32 c carry)
//
// xg2 layout (u16): off = ((g*256 + t)*2048) + tile*64 + c16*4 + row4
//   g = b>>2, row4 = b&3 (= p), tile = col>>4, c16 = col&15.
//   Scan lane (w,quad,l16) gate j reads u16 at (w+8j)*64 + l16*4 + quad.

static __device__ __forceinline__ u16 bf16bits(float v) {
  return __builtin_bit_cast(u16, (bf16_t)v);
}
static __device__ __forceinline__ float bf16f(u16 v) {
  return __builtin_bit_cast(float, (u32)v << 16);
}

__global__ __launch_bounds__(256) void k_cvt_emb(const float* __restrict__ e,
                                                 u16* __restrict__ o, int n) {
  int i = blockIdx.x * 256 + threadIdx.x;
  if (i < n) o[i] = bf16bits(e[i]);
}

// WkT[n][k] = Wk[k][n]  (Wk is [256][512] row-major)
__global__ __launch_bounds__(256) void k_wkt(const float* __restrict__ wk,
                                             u16* __restrict__ o) {
  int i = blockIdx.x * 256 + threadIdx.x;  // 131072 total
  int k = i & 255, n = i >> 8;
  o[i] = bf16bits(wk[k * 512 + n]);
}

// xg2 = (emb[x] @ Wk + bias) * gate_scale, bf16, scan-tiled layout.
// Barrier-free K-loop: 512 thr/wg, wave w holds its whole B slice
// (cols 64w..64w+63, all K) in 128 VGPRs; A staged to LDS once; no
// per-kt staging/syncs (R7 had 16 barriers + 8 vmcnt(0) drains per wg).
__global__ __launch_bounds__(512, 2) void k_xgemm(
    const int* __restrict__ x, const u16* __restrict__ embb,
    const u16* __restrict__ wkt, const float* __restrict__ bias,
    u16* __restrict__ xg, int t0) {
  __shared__ u16 Al[64 * LDA];
  __shared__ float biasl[512];
  const int tid = threadIdx.x;
  const int gg = blockIdx.x >> 6;   // 0..15: batch group of 16 rows
  const int tb = blockIdx.x & 63;   // 0..63: step group of 4
  const int w = tid >> 6, lane = tid & 63;
  const int l16 = lane & 15, quad = lane >> 4;

  // B preload into registers: bfr[nt][kt] = wkt[(64w+16nt+l16)*256 + kt*32 + quad*8]
  bf16x8 bfr[4][8];
#pragma unroll
  for (int nt = 0; nt < 4; ++nt) {
    const u16* bp = wkt + (64 * w + 16 * nt + l16) * 256 + quad * 8;
#pragma unroll
    for (int kt = 0; kt < 8; ++kt)
      bfr[nt][kt] = *(const bf16x8*)(bp + kt * 32);
  }

  // A gather: 64 rows x 256 bf16 -> LDS (once). flat uint4 f = p*512+tid.
#pragma unroll
  for (int p = 0; p < 4; ++p) {
    int f = p * 512 + tid;
    int lr = f >> 5, ch = f & 31;   // row 0..63, 16B-chunk 0..31
    int xi = (16 * gg + (lr & 15)) * 1024 + t0 + tb * 4 + (lr >> 4);
    int idx = x[xi];
    *(uint4*)&Al[lr * LDA + ch * 8] = *(const uint4*)&embb[idx * 256 + ch * 8];
  }
  biasl[tid] = bias[tid];
  __syncthreads();

  f32x4 acc[4][4];  // [mt][nt]
#pragma unroll
  for (int mt = 0; mt < 4; ++mt)
#pragma unroll
    for (int nt = 0; nt < 4; ++nt) acc[mt][nt] = f32x4{0.f, 0.f, 0.f, 0.f};

#pragma unroll
  for (int kt = 0; kt < 8; ++kt) {
    bf16x8 a[4];
#pragma unroll
    for (int mt = 0; mt < 4; ++mt)
      a[mt] = *(const bf16x8*)&Al[(mt * 16 + l16) * LDA + kt * 32 + quad * 8];
#pragma unroll
    for (int nt = 0; nt < 4; ++nt)
#pragma unroll
      for (int mt = 0; mt < 4; ++mt)
        acc[mt][nt] =
            __builtin_amdgcn_mfma_f32_16x16x32_bf16(a[mt], bfr[nt][kt], acc[mt][nt], 0, 0, 0);
  }

  // epilogue: (acc + bias) * gsc; pack rows r=0..3 of scan-group g'=4gg+quad.
  // col = 64w + 16nt + l16 -> gate = w>>1 (wave-uniform); tile = 4w + nt.
  const float gsc = ((w >> 1) == 2) ? 1.0f : -LOG2E;
  const size_t gtbase = ((size_t)(4 * gg + quad) * 256 + tb * 4) * 2048;
#pragma unroll
  for (int nt = 0; nt < 4; ++nt) {
    float bv = biasl[64 * w + 16 * nt + l16];
    int tile = 4 * w + nt;
#pragma unroll
    for (int mt = 0; mt < 4; ++mt) {
      u64 pk = 0;
#pragma unroll
      for (int r = 0; r < 4; ++r)
        pk |= (u64)bf16bits((acc[mt][nt][r] + bv) * gsc) << (16 * r);
      size_t off = gtbase + (size_t)mt * 2048 + tile * 64 + l16 * 4;
      *(u64*)&xg[off] = pk;
    }
  }
}

// MFMA scan (unchanged from R7): 64 wgs x 512 thr; wg g owns batch rows
// 4g..4g+3 in M-slots {0,4,8,12}; every lane owns unit (row quad, col
// u=16w+l16), gates acc[0..3][0]. Lane-constant addresses; zrow broadcast
// for zero A-slots; xg seeds MFMA C; gates pre-scaled by -log2e.
__global__ __launch_bounds__(512) void k_scan(
    const u16* __restrict__ xg, const float* __restrict__ Wr,
    const float* __restrict__ Wd, const float* __restrict__ bd,
    float* __restrict__ hstf, float* __restrict__ cstf,
    float* __restrict__ out, int chunk) {
  const int g = blockIdx.x;
  const int tid = threadIdx.x;
  const int w = tid >> 6, lane = tid & 63;
  const int l16 = lane & 15, quad = lane >> 4;
  const int u = 16 * w + l16;

  __shared__ __align__(16) u16 hbuf[2][4 * 144];
  __shared__ __align__(16) u16 zrow[128];

  bf16x8 wf[4][4];
#pragma unroll
  for (int j = 0; j < 4; ++j) {
    const float sj = (j == 2) ? 1.0f : -LOG2E;
#pragma unroll
    for (int kt = 0; kt < 4; ++kt) {
      const float* p = Wr + (kt * 32 + quad * 8) * 512 + u + 128 * j;
#pragma unroll
      for (int jj = 0; jj < 8; ++jj) wf[j][kt][jj] = (bf16_t)(p[jj * 512] * sj);
    }
  }

  if (tid < 128) zrow[tid] = 0;

  float c1 = 0.f, h1 = 0.f;
  if (chunk != 0) {
    c1 = cstf[(g * 4 + quad) * 128 + u];
    h1 = hstf[(g * 4 + quad) * 128 + u];
  }
  hbuf[0][quad * 144 + u] = bf16bits(h1);

  const bool ald = (l16 & 3) == 0;
  const u16* rd0 = ald ? &hbuf[0][(l16 >> 2) * 144 + quad * 8] : &zrow[quad * 8];
  const u16* rd1 = ald ? &hbuf[1][(l16 >> 2) * 144 + quad * 8] : &zrow[quad * 8];
  u16* wr0 = &hbuf[0][quad * 144 + u];
  u16* wr1 = &hbuf[1][quad * 144 + u];

  const u16* xp = xg + (size_t)g * TC * 2048 + w * 64 + l16 * 4 + quad;
  u16 xq0[4], xq1[4];
#pragma unroll
  for (int j = 0; j < 4; ++j) xq0[j] = xp[j * 512];
#pragma unroll
  for (int j = 0; j < 4; ++j) xq1[j] = xp[2048 + j * 512];
  xp += 2 * 2048;

  __syncthreads();

  auto halfstep = [&](const u16* rd, u16* wr, u16* xv) {
    bf16x8 a[4];
#pragma unroll
    for (int kt = 0; kt < 4; ++kt)
      a[kt] = *(const bf16x8*)(rd + kt * 32);
    f32x4 acc[4];
#pragma unroll
    for (int j = 0; j < 4; ++j)
      acc[j] = f32x4{bf16f(xv[j]), 0.f, 0.f, 0.f};
#pragma unroll
    for (int j = 0; j < 4; ++j)
#pragma unroll
      for (int kt = 0; kt < 4; ++kt)
        acc[j] = __builtin_amdgcn_mfma_f32_16x16x32_bf16(a[kt], wf[j][kt], acc[j], 0, 0, 0);
#pragma unroll
    for (int j = 0; j < 4; ++j) xv[j] = xp[j * 512];
    xp += 2048;
    float ig = __builtin_amdgcn_rcpf(1.f + EXP2F(acc[0][0]));
    float fg = __builtin_amdgcn_rcpf(1.f + EXP2F(acc[1][0]));
    float og = __builtin_amdgcn_rcpf(1.f + EXP2F(acc[3][0]));
    float gg = fmaxf(acc[2][0], 0.f);
    c1 = fg * c1 + ig * gg;
    h1 = og * fmaxf(c1, 0.f);
    *wr = bf16bits(h1);
    LDS_BARRIER();
  };

  for (int t2 = 0; t2 < TC; t2 += 2) {
    halfstep(rd0, wr1, xq0);
    halfstep(rd1, wr0, xq1);
  }

  if (chunk != NCHUNK - 1) {
    cstf[(g * 4 + quad) * 128 + u] = c1;
    hstf[(g * 4 + quad) * 128 + u] = h1;
  } else if (tid < 8) {
    int p = tid >> 1, jo = tid & 1;
    float o = bd[jo];
    for (int k = 0; k < 128; ++k)
      o += bf16f(hbuf[0][p * 144 + k]) * Wd[k * 2 + jo];
    out[(g * 4 + p) * 2 + jo] = o;
  }
}

extern "C" void kernel_launch(void* const* d_in, const int* in_sizes, int n_in,
                              void* d_out, int out_size, void* d_ws, size_t ws_size,
                              hipStream_t stream) {
  const int* x = (const int*)d_in[0];
  const float* emb = (const float*)d_in[1];
  const float* Wk = (const float*)d_in[2];
  const float* Wr = (const float*)d_in[3];
  const float* bias = (const float*)d_in[4];
  const float* Wd = (const float*)d_in[5];
  const float* bd = (const float*)d_in[6];
  float* out = (float*)d_out;
  char* ws = (char*)d_ws;
  u16* xg = (u16*)(ws);
  u16* embb = (u16*)(ws + 67108864);
  u16* wkt = (u16*)(ws + 72228864);
  float* hst = (float*)(ws + 72491008);
  float* cst = (float*)(ws + 72622080);

  k_cvt_emb<<<10000, 256, 0, stream>>>(emb, embb, 2560000);
  k_wkt<<<512, 256, 0, stream>>>(Wk, wkt);
  for (int chunk = 0; chunk < NCHUNK; ++chunk) {
    k_xgemm<<<1024, 512, 0, stream>>>(x, embb, wkt, bias, xg, chunk * TC);
    k_scan<<<64, 512, 0, stream>>>(xg, Wr, Wd, bd, hst, cst, out, chunk);
  }
}